// Round 1
// baseline (1197.196 us; speedup 1.0000x reference)
//
#include <hip/hip_runtime.h>
#include <math.h>

#define VOL 262144        // 64^3
#define EPSF 1e-5f

__device__ __forceinline__ float waveReduceSum(float v) {
    #pragma unroll
    for (int off = 32; off > 0; off >>= 1) v += __shfl_down(v, off);
    return v;
}

// K1: directional pools. One block per (bg,cc) row r in [0,128).
// cat[r*192 + {0..63:d, 64..127:h, 128..191:w}] = means.
__global__ void k_pools(const float* __restrict__ x, float* __restrict__ cat) {
    int r = blockIdx.x;
    const float* base = x + (size_t)r * VOL;
    __shared__ float sd[64], sh_[64], sw_[64];
    int tid = threadIdx.x;
    if (tid < 64) { sd[tid] = 0.f; sh_[tid] = 0.f; sw_[tid] = 0.f; }
    __syncthreads();
    int w = tid & 63, hb = tid >> 6;      // 4 h-groups of 16
    int lane = tid & 63;
    float accW = 0.f;
    float accH[16];
    #pragma unroll
    for (int j = 0; j < 16; j++) accH[j] = 0.f;
    for (int d = 0; d < 64; d++) {
        const float* pd = base + (d << 12);
        float psum = 0.f;
        #pragma unroll
        for (int j = 0; j < 16; j++) {
            float v = pd[((hb * 16 + j) << 6) + w];
            accW += v; accH[j] += v; psum += v;
        }
        psum = waveReduceSum(psum);
        if (lane == 0) atomicAdd(&sd[d], psum);
    }
    atomicAdd(&sw_[w], accW);
    #pragma unroll
    for (int j = 0; j < 16; j++) atomicAdd(&sh_[hb * 16 + j], accH[j]);
    __syncthreads();
    if (tid < 64) {
        const float inv = 1.f / 4096.f;
        float* o = cat + (size_t)r * 192;
        o[tid]        = sd[tid]  * inv;
        o[64 + tid]   = sh_[tid] * inv;
        o[128 + tid]  = sw_[tid] * inv;
    }
}

// K2: hwd = W1·cat + b1; BN over (bg,s) per channel (3072 vals); relu; sigmoid -> a.
// Single block, 256 threads. a layout: a[(bg*8+o)*192 + s].
__global__ void k_attn(const float* __restrict__ cat, const float* __restrict__ w1,
                       const float* __restrict__ b1, const float* __restrict__ g1,
                       const float* __restrict__ be1, float* __restrict__ aout) {
    __shared__ float r1[256], r2[256];
    __shared__ float bsc[8], bsh[8];
    __shared__ float wsm[64];
    int tid = threadIdx.x;
    if (tid < 64) wsm[tid] = w1[tid];
    __syncthreads();
    int o = tid >> 5, j = tid & 31;
    float s1 = 0.f, s2 = 0.f;
    for (int idx = j; idx < 3072; idx += 32) {
        int bgI = idx / 192, s = idx - bgI * 192;
        const float* cp = cat + (size_t)bgI * 1536 + s;
        float h = b1[o];
        #pragma unroll
        for (int i = 0; i < 8; i++) h += wsm[o * 8 + i] * cp[i * 192];
        s1 += h; s2 += h * h;
    }
    r1[tid] = s1; r2[tid] = s2;
    __syncthreads();
    for (int st = 16; st > 0; st >>= 1) {
        if (j < st) { r1[tid] += r1[tid + st]; r2[tid] += r2[tid + st]; }
        __syncthreads();
    }
    if (j == 0) {
        float mean = r1[tid] / 3072.f;
        float var  = r2[tid] / 3072.f - mean * mean;
        float sc = g1[o] * rsqrtf(var + EPSF);
        bsc[o] = sc; bsh[o] = be1[o] - mean * sc;
    }
    __syncthreads();
    for (int e = tid; e < 24576; e += 256) {
        int bgI = e / 1536;
        int rem = e - bgI * 1536;
        int oo = rem / 192;
        int s = rem - oo * 192;
        const float* cp = cat + (size_t)bgI * 1536 + s;
        float h = b1[oo];
        #pragma unroll
        for (int i = 0; i < 8; i++) h += wsm[oo * 8 + i] * cp[i * 192];
        float v = bsc[oo] * h + bsh[oo];
        v = fmaxf(v, 0.f);
        aout[e] = 1.f / (1.f + expf(-v));
    }
}

// K3: GroupNorm stats of y = x * a_d[d]*a_h[h]*a_w[w]. One block per row r.
__global__ void k_gnstats(const float* __restrict__ x, const float* __restrict__ a,
                          float* __restrict__ gmean, float* __restrict__ grstd) {
    int r = blockIdx.x;
    const float* xp = x + (size_t)r * VOL;
    const float* ap = a + (size_t)r * 192;
    __shared__ float A[192];
    __shared__ float wred[8];
    int tid = threadIdx.x;
    if (tid < 192) A[tid] = ap[tid];
    __syncthreads();
    float s1 = 0.f, s2 = 0.f;
    for (int n = tid; n < VOL; n += 256) {
        int d = n >> 12, h = (n >> 6) & 63, w = n & 63;
        float av = A[d] * A[64 + h] * A[128 + w];
        float y = xp[n] * av;
        s1 += y; s2 += y * y;
    }
    s1 = waveReduceSum(s1); s2 = waveReduceSum(s2);
    int lane = tid & 63, wid = tid >> 6;
    if (lane == 0) { wred[wid] = s1; wred[4 + wid] = s2; }
    __syncthreads();
    if (tid == 0) {
        float t1 = wred[0] + wred[1] + wred[2] + wred[3];
        float t2 = wred[4] + wred[5] + wred[6] + wred[7];
        float mean = t1 / (float)VOL;
        float var  = t2 / (float)VOL - mean * mean;
        gmean[r] = mean;
        grstd[r] = rsqrtf(var + EPSF);
    }
}

// K4: 3x3x3 SAME conv, 8->8 ch per sample, + bias; store raw; accumulate BN sums.
// Weights read with wave-uniform indices -> scalar loads (free broadcast).
#define CONV_GRID 2048
__global__ void k_conv(const float* __restrict__ x, const float* __restrict__ w3,
                       const float* __restrict__ b3, float* __restrict__ x2raw,
                       float* __restrict__ stats) {
    __shared__ float wred[64];
    int tid = threadIdx.x;
    float ps[8], pq[8];
    #pragma unroll
    for (int c = 0; c < 8; c++) { ps[c] = 0.f; pq[c] = 0.f; }
    for (int chunk = blockIdx.x; chunk < 16384; chunk += CONV_GRID) {
        int bg = chunk >> 10;
        int n = ((chunk & 1023) << 8) + tid;
        int d = n >> 12, h = (n >> 6) & 63, w = n & 63;
        float acc[8];
        #pragma unroll
        for (int c = 0; c < 8; c++) acc[c] = b3[c];
        const float* xb = x + ((size_t)bg << 21);     // bg*8*VOL
        #pragma unroll
        for (int ic = 0; ic < 8; ic++) {
            const float* p = xb + ((size_t)ic << 18);
            #pragma unroll
            for (int kd = 0; kd < 3; kd++) {
                int dd = d + kd - 1;
                if ((unsigned)dd >= 64u) continue;     // wave-uniform (d const per chunk)
                #pragma unroll
                for (int kh = 0; kh < 3; kh++) {
                    int hh = h + kh - 1;
                    if ((unsigned)hh >= 64u) continue; // wave-uniform (h const per wave)
                    const float* row = p + (dd << 12) + (hh << 6);
                    float vm = (w > 0)  ? row[w - 1] : 0.f;
                    float vc = row[w];
                    float vp = (w < 63) ? row[w + 1] : 0.f;
                    int tb = (kd * 3 + kh) * 3;
                    #pragma unroll
                    for (int oc = 0; oc < 8; oc++) {
                        const float* wp = w3 + (oc * 8 + ic) * 27 + tb;
                        acc[oc] += vm * wp[0] + vc * wp[1] + vp * wp[2];
                    }
                }
            }
        }
        size_t ob = ((size_t)bg << 21) + n;
        #pragma unroll
        for (int oc = 0; oc < 8; oc++) {
            float v = acc[oc];
            x2raw[ob + ((size_t)oc << 18)] = v;
            ps[oc] += v; pq[oc] += v * v;
        }
    }
    int lane = tid & 63, wid = tid >> 6;
    #pragma unroll
    for (int q = 0; q < 8; q++) {
        float v1 = waveReduceSum(ps[q]);
        float v2 = waveReduceSum(pq[q]);
        if (lane == 0) { wred[wid * 16 + q] = v1; wred[wid * 16 + 8 + q] = v2; }
    }
    __syncthreads();
    if (tid < 16) {
        float t = wred[tid] + wred[16 + tid] + wred[32 + tid] + wred[48 + tid];
        atomicAdd(&stats[tid], t);
    }
}

// K5: finalize BN3 scale/shift; x11 = softmax(gn_b)  (x1 spatial mean == gn_b exactly).
__global__ void k_finalize(const float* __restrict__ stats, const float* __restrict__ g3,
                           const float* __restrict__ be3, const float* __restrict__ gnb,
                           float* __restrict__ bnp, float* __restrict__ x11) {
    int tid = threadIdx.x;
    if (tid < 8) {
        float N = 16.f * (float)VOL;
        float mean = stats[tid] / N;
        float var  = stats[8 + tid] / N - mean * mean;
        float sc = g3[tid] * rsqrtf(var + EPSF);
        bnp[tid] = sc; bnp[8 + tid] = be3[tid] - mean * sc;
    }
    if (tid == 0) {
        float m = -1e30f;
        for (int c = 0; c < 8; c++) m = fmaxf(m, gnb[c]);
        float e[8], sum = 0.f;
        for (int c = 0; c < 8; c++) { e[c] = expf(gnb[c] - m); sum += e[c]; }
        for (int c = 0; c < 8; c++) x11[c] = e[c] / sum;
    }
}

// K6: per-row mean of relu(bn(x2raw)) -> mrelu (raw sums, atomically accumulated).
__global__ void k_relumean(const float* __restrict__ x2raw, const float* __restrict__ bnp,
                           float* __restrict__ mrelu) {
    int blk = blockIdx.x;              // 1024 blocks: 8 per row
    int r = blk >> 3, part = blk & 7;
    int cc = r & 7;
    float sc = bnp[cc], sh = bnp[8 + cc];
    const float* p = x2raw + (size_t)r * VOL + part * 32768;
    int tid = threadIdx.x;
    float s = 0.f;
    for (int i = tid; i < 32768; i += 256) s += fmaxf(sc * p[i] + sh, 0.f);
    s = waveReduceSum(s);
    __shared__ float wred[4];
    int lane = tid & 63, wid = tid >> 6;
    if (lane == 0) wred[wid] = s;
    __syncthreads();
    if (tid == 0) atomicAdd(&mrelu[r], wred[0] + wred[1] + wred[2] + wred[3]);
}

// K6b: x21[bg][c] = softmax_c(mrelu[bg*8+c]/VOL)
__global__ void k_soft21(const float* __restrict__ mrelu, float* __restrict__ x21) {
    int bg = threadIdx.x;
    if (bg < 16) {
        float v[8], m = -1e30f;
        for (int c = 0; c < 8; c++) { v[c] = mrelu[bg * 8 + c] / (float)VOL; m = fmaxf(m, v[c]); }
        float sum = 0.f;
        for (int c = 0; c < 8; c++) { v[c] = expf(v[c] - m); sum += v[c]; }
        for (int c = 0; c < 8; c++) x21[bg * 8 + c] = v[c] / sum;
    }
}

// K7: final fused: weights = x11·x22 + x21·x12; out = x * sigmoid(weights)
__global__ void k_final(const float* __restrict__ x, const float* __restrict__ x2raw,
                        const float* __restrict__ a, const float* __restrict__ bnp,
                        const float* __restrict__ x11g, const float* __restrict__ x21g,
                        const float* __restrict__ gmean, const float* __restrict__ grstd,
                        const float* __restrict__ gng, const float* __restrict__ gnb,
                        float* __restrict__ out) {
    int bg = blockIdx.x >> 10;
    int tid = threadIdx.x;
    int n = ((blockIdx.x & 1023) << 8) + tid;
    __shared__ float sa[1536];
    __shared__ float sc_[8], sh_[8], sx11[8], sx21[8], sgsc[8], sgsh[8];
    const float* ap = a + (size_t)bg * 1536;
    for (int i = tid; i < 1536; i += 256) sa[i] = ap[i];
    if (tid < 8) {
        sc_[tid] = bnp[tid]; sh_[tid] = bnp[8 + tid];
        sx11[tid] = x11g[tid]; sx21[tid] = x21g[bg * 8 + tid];
        float gr = grstd[bg * 8 + tid] * gng[tid];
        sgsc[tid] = gr; sgsh[tid] = gnb[tid] - gmean[bg * 8 + tid] * gr;
    }
    __syncthreads();
    int d = n >> 12, h = (n >> 6) & 63, w = n & 63;
    size_t base = ((size_t)bg << 21) + n;
    float xr[8], wsum = 0.f;
    #pragma unroll
    for (int c = 0; c < 8; c++) {
        size_t idx = base + ((size_t)c << 18);
        float xv = x[idx]; xr[c] = xv;
        float v2 = x2raw[idx];
        float x22 = fmaxf(sc_[c] * v2 + sh_[c], 0.f);
        float av = sa[c * 192 + d] * sa[c * 192 + 64 + h] * sa[c * 192 + 128 + w];
        float x12 = (xv * av) * sgsc[c] + sgsh[c];
        wsum += sx11[c] * x22 + sx21[c] * x12;
    }
    float sig = 1.f / (1.f + __expf(-wsum));
    #pragma unroll
    for (int c = 0; c < 8; c++) out[base + ((size_t)c << 18)] = xr[c] * sig;
}

extern "C" void kernel_launch(void* const* d_in, const int* in_sizes, int n_in,
                              void* d_out, int out_size, void* d_ws, size_t ws_size,
                              hipStream_t stream) {
    const float* x   = (const float*)d_in[0];
    const float* w1  = (const float*)d_in[1];
    const float* b1  = (const float*)d_in[2];
    const float* g1  = (const float*)d_in[3];
    const float* be1 = (const float*)d_in[4];
    const float* w3  = (const float*)d_in[5];
    const float* b3  = (const float*)d_in[6];
    const float* g3  = (const float*)d_in[7];
    const float* be3 = (const float*)d_in[8];
    const float* gng = (const float*)d_in[9];
    const float* gnb = (const float*)d_in[10];
    float* out = (float*)d_out;

    float* ws     = (float*)d_ws;
    float* x2raw  = ws;                       // 128*VOL = 33554432 floats
    float* cat    = ws + 33554432;            // 24576
    float* a      = cat + 24576;              // 24576
    float* stats  = a + 24576;                // 16
    float* bnp    = stats + 16;               // 16
    float* x11    = bnp + 16;                 // 8
    float* gmean  = x11 + 8;                  // 128
    float* grstd  = gmean + 128;              // 128
    float* mrelu  = grstd + 128;              // 128
    float* x21    = mrelu + 128;              // 128

    // zero small accumulators (stats..x21 region)
    hipMemsetAsync(stats, 0, (16 + 16 + 8 + 128 * 4) * sizeof(float), stream);

    k_pools   <<<128, 256, 0, stream>>>(x, cat);
    k_attn    <<<1, 256, 0, stream>>>(cat, w1, b1, g1, be1, a);
    k_gnstats <<<128, 256, 0, stream>>>(x, a, gmean, grstd);
    k_conv    <<<CONV_GRID, 256, 0, stream>>>(x, w3, b3, x2raw, stats);
    k_finalize<<<1, 64, 0, stream>>>(stats, g3, be3, gnb, bnp, x11);
    k_relumean<<<1024, 256, 0, stream>>>(x2raw, bnp, mrelu);
    k_soft21  <<<1, 64, 0, stream>>>(mrelu, x21);
    k_final   <<<16384, 256, 0, stream>>>(x, x2raw, a, bnp, x11, x21, gmean, grstd, gng, gnb, out);
}

// Round 2
// 725.508 us; speedup vs baseline: 1.6501x; 1.6501x over previous
//
#include <hip/hip_runtime.h>
#include <math.h>

#define VOL 262144        // 64^3
#define EPSF 1e-5f

__device__ __forceinline__ float waveReduceSum(float v) {
    #pragma unroll
    for (int off = 32; off > 0; off >>= 1) v += __shfl_down(v, off);
    return v;
}

// ---------------------------------------------------------------------------
// K1: directional pool SUMS. 1024 blocks: r = blk>>3 (row 0..127), part = blk&7
// (d-range of 8 planes). Outputs atomically accumulated raw sums into
// catS[r*192 + {0..63: d, 64..127: h, 128..191: w}].
// ---------------------------------------------------------------------------
__global__ void k_pools(const float* __restrict__ x, float* __restrict__ catS) {
    int r = blockIdx.x >> 3, part = blockIdx.x & 7;
    const float* base = x + (size_t)r * VOL + ((size_t)(part * 8) << 12);
    __shared__ float sd[8], sh[64], sw[64];
    int tid = threadIdx.x;
    if (tid < 8) sd[tid] = 0.f;
    if (tid < 64) { sh[tid] = 0.f; sw[tid] = 0.f; }
    __syncthreads();
    int w4 = (tid & 15) * 4;      // float4 column
    int hr = tid >> 4;            // 0..15
    float wacc[4] = {0.f, 0.f, 0.f, 0.f};
    float hacc[4] = {0.f, 0.f, 0.f, 0.f};
    for (int p = 0; p < 8; p++) {
        const float* pd = base + (p << 12);
        float psum = 0.f;
        #pragma unroll
        for (int j = 0; j < 4; j++) {
            int hh = hr + j * 16;
            float4 v = *(const float4*)(pd + (hh << 6) + w4);
            float s = v.x + v.y + v.z + v.w;
            hacc[j] += s; psum += s;
            wacc[0] += v.x; wacc[1] += v.y; wacc[2] += v.z; wacc[3] += v.w;
        }
        psum = waveReduceSum(psum);
        if ((tid & 63) == 0) atomicAdd(&sd[p], psum);
    }
    #pragma unroll
    for (int j = 0; j < 4; j++) atomicAdd(&sh[hr + j * 16], hacc[j]);
    #pragma unroll
    for (int k = 0; k < 4; k++) atomicAdd(&sw[w4 + k], wacc[k]);
    __syncthreads();
    float* o = catS + (size_t)r * 192;
    if (tid < 8)                       atomicAdd(&o[part * 8 + tid], sd[tid]);
    else if (tid >= 64 && tid < 128)   atomicAdd(&o[64 + tid - 64], sh[tid - 64]);
    else if (tid >= 128 && tid < 192)  atomicAdd(&o[128 + tid - 128], sw[tid - 128]);
}

// ---------------------------------------------------------------------------
// K2a: BN stats of hwd over (bg,s) per channel. catS holds SUMS -> weights
// pre-scaled by 1/4096. Single block. Writes attnp[0..7]=scale, [8..15]=shift.
// ---------------------------------------------------------------------------
__global__ void k_attn_stats(const float* __restrict__ catS, const float* __restrict__ w1,
                             const float* __restrict__ b1, const float* __restrict__ g1,
                             const float* __restrict__ be1, float* __restrict__ attnp) {
    __shared__ float r1[256], r2[256];
    __shared__ float wsm[64];
    int tid = threadIdx.x;
    if (tid < 64) wsm[tid] = w1[tid] * (1.f / 4096.f);
    __syncthreads();
    int o = tid >> 5, j = tid & 31;
    float s1 = 0.f, s2 = 0.f;
    for (int idx = j; idx < 3072; idx += 32) {
        int bgI = idx / 192, s = idx - bgI * 192;
        const float* cp = catS + (size_t)bgI * 1536 + s;
        float h = b1[o];
        #pragma unroll
        for (int i = 0; i < 8; i++) h += wsm[o * 8 + i] * cp[i * 192];
        s1 += h; s2 += h * h;
    }
    r1[tid] = s1; r2[tid] = s2;
    __syncthreads();
    for (int st = 16; st > 0; st >>= 1) {
        if (j < st) { r1[tid] += r1[tid + st]; r2[tid] += r2[tid + st]; }
        __syncthreads();
    }
    if (j == 0) {
        float mean = r1[tid] / 3072.f;
        float var  = r2[tid] / 3072.f - mean * mean;
        float sc = g1[o] * rsqrtf(var + EPSF);
        attnp[o] = sc; attnp[8 + o] = be1[o] - mean * sc;
    }
}

// K2b: apply BN+relu+sigmoid -> a. 96 blocks x 256, one element each.
__global__ void k_attn_apply(const float* __restrict__ catS, const float* __restrict__ w1,
                             const float* __restrict__ b1, const float* __restrict__ attnp,
                             float* __restrict__ aout) {
    __shared__ float wsm[64];
    int tid = threadIdx.x;
    if (tid < 64) wsm[tid] = w1[tid] * (1.f / 4096.f);
    __syncthreads();
    int e = blockIdx.x * 256 + tid;     // < 24576
    int bgI = e / 1536;
    int rem = e - bgI * 1536;
    int oo = rem / 192;
    int s = rem - oo * 192;
    const float* cp = catS + (size_t)bgI * 1536 + s;
    float h = b1[oo];
    #pragma unroll
    for (int i = 0; i < 8; i++) h += wsm[oo * 8 + i] * cp[i * 192];
    float v = attnp[oo] * h + attnp[8 + oo];
    v = fmaxf(v, 0.f);
    aout[e] = 1.f / (1.f + __expf(-v));
}

// ---------------------------------------------------------------------------
// K3: GroupNorm raw sums of y = x * a_d*a_h*a_w. 1024 blocks (8 per row).
// gs[r] += sum(y), gs[128+r] += sum(y^2).
// ---------------------------------------------------------------------------
__global__ void k_gnstats(const float* __restrict__ x, const float* __restrict__ a,
                          float* __restrict__ gs) {
    int r = blockIdx.x >> 3, part = blockIdx.x & 7;
    const float* xp = x + (size_t)r * VOL + ((size_t)part << 15);
    __shared__ float A[192];
    __shared__ float wred[8];
    int tid = threadIdx.x;
    if (tid < 192) A[tid] = a[(size_t)r * 192 + tid];
    __syncthreads();
    float s1 = 0.f, s2 = 0.f;
    for (int it = 0; it < 32; it++) {
        int e4 = it * 256 + tid;          // float4 index in [0, 8192)
        int n = e4 * 4;
        int dl = n >> 12;                 // 0..7
        int h = (n >> 6) & 63, w = n & 63;
        float4 v = *(const float4*)(xp + n);
        float adh = A[part * 8 + dl] * A[64 + h];
        float y0 = v.x * adh * A[128 + w];
        float y1 = v.y * adh * A[128 + w + 1];
        float y2 = v.z * adh * A[128 + w + 2];
        float y3 = v.w * adh * A[128 + w + 3];
        s1 += y0 + y1 + y2 + y3;
        s2 += y0 * y0 + y1 * y1 + y2 * y2 + y3 * y3;
    }
    s1 = waveReduceSum(s1); s2 = waveReduceSum(s2);
    int lane = tid & 63, wid = tid >> 6;
    if (lane == 0) { wred[wid] = s1; wred[4 + wid] = s2; }
    __syncthreads();
    if (tid == 0) {
        atomicAdd(&gs[r],       wred[0] + wred[1] + wred[2] + wred[3]);
        atomicAdd(&gs[128 + r], wred[4] + wred[5] + wred[6] + wred[7]);
    }
}

// ---------------------------------------------------------------------------
// K4: 3x3x3 SAME conv, rolling-d column form. 1024 blocks:
// bg(16) x dchunk(4) x hblk(16); thread = (h = hblk*4 + wave, w = lane),
// walks 18 input planes, 3 rotating accumulator sets of 8 oc.
// w-neighbors via shfl (lane == w). Weights: wave-uniform -> scalar loads.
// ---------------------------------------------------------------------------
__global__ __launch_bounds__(256) void k_conv(const float* __restrict__ x,
                                              const float* __restrict__ w3,
                                              const float* __restrict__ b3,
                                              float* __restrict__ x2raw,
                                              float* __restrict__ stats) {
    __shared__ float wred[64];
    int blk = blockIdx.x;
    int bg = blk >> 6;
    int rem = blk & 63;
    int d0 = (rem >> 4) * 16;
    int hblk = rem & 15;
    int tid = threadIdx.x;
    int w = tid & 63;                 // == lane
    int h = hblk * 4 + (tid >> 6);
    const float* xb = x + ((size_t)bg << 21);
    float acc[3][8];
    float ps[8], pq[8];
    #pragma unroll
    for (int c = 0; c < 8; c++) { ps[c] = 0.f; pq[c] = 0.f; }

#define STEP(I, ZI, YI, XI)                                                       \
    {                                                                             \
        int dd = d0 - 1 + (I);                                                    \
        bool dvalid = (dd >= 0) && (dd < 64);                                     \
        _Pragma("unroll")                                                         \
        for (int c = 0; c < 8; c++) acc[ZI][c] = b3[c];                           \
        _Pragma("unroll 1")                                                       \
        for (int ic = 0; ic < 8; ic++) {                                          \
            const float* pl = xb + ((size_t)ic << 18) + ((size_t)(dd & 63) << 12) + w; \
            float v[3][3];                                                        \
            _Pragma("unroll")                                                     \
            for (int kh = 0; kh < 3; kh++) {                                      \
                int hh = h + kh - 1;                                              \
                float vc = 0.f;                                                   \
                if (dvalid && hh >= 0 && hh < 64) vc = pl[hh << 6];               \
                float vm = __shfl_up(vc, 1);                                      \
                float vp = __shfl_down(vc, 1);                                    \
                if (w == 0)  vm = 0.f;                                            \
                if (w == 63) vp = 0.f;                                            \
                v[kh][0] = vm; v[kh][1] = vc; v[kh][2] = vp;                      \
            }                                                                     \
            const float* wb = w3 + ic * 27;                                       \
            _Pragma("unroll")                                                     \
            for (int oc = 0; oc < 8; oc++) {                                      \
                const float* wo = wb + oc * 216;                                  \
                _Pragma("unroll")                                                 \
                for (int kh = 0; kh < 3; kh++) {                                  \
                    _Pragma("unroll")                                             \
                    for (int kw = 0; kw < 3; kw++) {                              \
                        float vv = v[kh][kw];                                     \
                        acc[ZI][oc] += vv * wo[kh * 3 + kw];                      \
                        acc[YI][oc] += vv * wo[9 + kh * 3 + kw];                  \
                        acc[XI][oc] += vv * wo[18 + kh * 3 + kw];                 \
                    }                                                             \
                }                                                                 \
            }                                                                     \
        }                                                                         \
        if ((I) >= 2) {                                                           \
            int dO = d0 - 2 + (I);                                                \
            size_t base = ((size_t)bg << 21) + ((size_t)dO << 12) + (h << 6) + w; \
            _Pragma("unroll")                                                     \
            for (int oc = 0; oc < 8; oc++) {                                      \
                float vv = acc[XI][oc];                                           \
                x2raw[base + ((size_t)oc << 18)] = vv;                            \
                ps[oc] += vv; pq[oc] += vv * vv;                                  \
            }                                                                     \
        }                                                                         \
    }

    for (int ib = 0; ib < 18; ib += 3) {
        STEP(ib + 0, 0, 2, 1)
        STEP(ib + 1, 1, 0, 2)
        STEP(ib + 2, 2, 1, 0)
    }
#undef STEP

    int lane = tid & 63, wid = tid >> 6;
    #pragma unroll
    for (int q = 0; q < 8; q++) {
        float v1 = waveReduceSum(ps[q]);
        float v2 = waveReduceSum(pq[q]);
        if (lane == 0) { wred[wid * 16 + q] = v1; wred[wid * 16 + 8 + q] = v2; }
    }
    __syncthreads();
    if (tid < 16) {
        float t = wred[tid] + wred[16 + tid] + wred[32 + tid] + wred[48 + tid];
        atomicAdd(&stats[tid], t);
    }
}

// K5: finalize BN3 scale/shift; x11 = softmax(gn_b) (x1 spatial mean == gn_b).
__global__ void k_finalize(const float* __restrict__ stats, const float* __restrict__ g3,
                           const float* __restrict__ be3, const float* __restrict__ gnb,
                           float* __restrict__ bnp, float* __restrict__ x11) {
    int tid = threadIdx.x;
    if (tid < 8) {
        float N = 16.f * (float)VOL;
        float mean = stats[tid] / N;
        float var  = stats[8 + tid] / N - mean * mean;
        float sc = g3[tid] * rsqrtf(var + EPSF);
        bnp[tid] = sc; bnp[8 + tid] = be3[tid] - mean * sc;
    }
    if (tid == 0) {
        float m = -1e30f;
        for (int c = 0; c < 8; c++) m = fmaxf(m, gnb[c]);
        float e[8], sum = 0.f;
        for (int c = 0; c < 8; c++) { e[c] = __expf(gnb[c] - m); sum += e[c]; }
        for (int c = 0; c < 8; c++) x11[c] = e[c] / sum;
    }
}

// K6: per-row sum of relu(bn(x2raw)) -> mrelu. 1024 blocks, float4.
__global__ void k_relumean(const float* __restrict__ x2raw, const float* __restrict__ bnp,
                           float* __restrict__ mrelu) {
    int blk = blockIdx.x;
    int r = blk >> 3, part = blk & 7;
    int cc = r & 7;
    float sc = bnp[cc], sh = bnp[8 + cc];
    const float4* p = (const float4*)(x2raw + (size_t)r * VOL + (size_t)part * 32768);
    int tid = threadIdx.x;
    float s = 0.f;
    for (int it = 0; it < 32; it++) {
        float4 v = p[it * 256 + tid];
        s += fmaxf(sc * v.x + sh, 0.f) + fmaxf(sc * v.y + sh, 0.f)
           + fmaxf(sc * v.z + sh, 0.f) + fmaxf(sc * v.w + sh, 0.f);
    }
    s = waveReduceSum(s);
    __shared__ float wred[4];
    int lane = tid & 63, wid = tid >> 6;
    if (lane == 0) wred[wid] = s;
    __syncthreads();
    if (tid == 0) atomicAdd(&mrelu[r], wred[0] + wred[1] + wred[2] + wred[3]);
}

// K6b: x21[bg][c] = softmax_c(mrelu[bg*8+c]/VOL)
__global__ void k_soft21(const float* __restrict__ mrelu, float* __restrict__ x21) {
    int bg = threadIdx.x;
    if (bg < 16) {
        float v[8], m = -1e30f;
        for (int c = 0; c < 8; c++) { v[c] = mrelu[bg * 8 + c] / (float)VOL; m = fmaxf(m, v[c]); }
        float sum = 0.f;
        for (int c = 0; c < 8; c++) { v[c] = __expf(v[c] - m); sum += v[c]; }
        for (int c = 0; c < 8; c++) x21[bg * 8 + c] = v[c] / sum;
    }
}

// ---------------------------------------------------------------------------
// K7: final fused: weights = x11·x22 + x21·x12; out = x * sigmoid(weights).
// float4 along w. 4096 blocks: bg = blk>>8, seg = blk&255.
// GroupNorm mean/rstd computed in preamble from raw sums gs.
// ---------------------------------------------------------------------------
__global__ void k_final(const float* __restrict__ x, const float* __restrict__ x2raw,
                        const float* __restrict__ a, const float* __restrict__ bnp,
                        const float* __restrict__ x11g, const float* __restrict__ x21g,
                        const float* __restrict__ gs, const float* __restrict__ gng,
                        const float* __restrict__ gnb, float* __restrict__ out) {
    int bg = blockIdx.x >> 8;
    int seg = blockIdx.x & 255;
    int tid = threadIdx.x;
    __shared__ float sa[1536];
    __shared__ float sc_[8], sh_[8], sx11[8], sx21[8], sgsc[8], sgsh[8];
    const float* ap = a + (size_t)bg * 1536;
    for (int i = tid; i < 1536; i += 256) sa[i] = ap[i];
    if (tid < 8) {
        int r = bg * 8 + tid;
        sc_[tid] = bnp[tid]; sh_[tid] = bnp[8 + tid];
        sx11[tid] = x11g[tid]; sx21[tid] = x21g[r];
        float mean = gs[r] / (float)VOL;
        float var  = gs[128 + r] / (float)VOL - mean * mean;
        float gr = rsqrtf(var + EPSF) * gng[tid];
        sgsc[tid] = gr; sgsh[tid] = gnb[tid] - mean * gr;
    }
    __syncthreads();
    int n = (seg * 256 + tid) * 4;       // element offset in [0, VOL)
    int d = n >> 12, h = (n >> 6) & 63, w = n & 63;
    size_t base = ((size_t)bg << 21) + n;
    float4 xr[8];
    float w0 = 0.f, w1 = 0.f, w2 = 0.f, w3 = 0.f;
    #pragma unroll
    for (int c = 0; c < 8; c++) {
        size_t idx = base + ((size_t)c << 18);
        float4 xv = *(const float4*)(x + idx);
        float4 v2 = *(const float4*)(x2raw + idx);
        xr[c] = xv;
        float adh = sa[c * 192 + d] * sa[c * 192 + 64 + h] * sgsc[c];
        float x22_0 = fmaxf(sc_[c] * v2.x + sh_[c], 0.f);
        float x22_1 = fmaxf(sc_[c] * v2.y + sh_[c], 0.f);
        float x22_2 = fmaxf(sc_[c] * v2.z + sh_[c], 0.f);
        float x22_3 = fmaxf(sc_[c] * v2.w + sh_[c], 0.f);
        float x12_0 = xv.x * (adh * sa[c * 192 + 128 + w])     + sgsh[c];
        float x12_1 = xv.y * (adh * sa[c * 192 + 128 + w + 1]) + sgsh[c];
        float x12_2 = xv.z * (adh * sa[c * 192 + 128 + w + 2]) + sgsh[c];
        float x12_3 = xv.w * (adh * sa[c * 192 + 128 + w + 3]) + sgsh[c];
        w0 += sx11[c] * x22_0 + sx21[c] * x12_0;
        w1 += sx11[c] * x22_1 + sx21[c] * x12_1;
        w2 += sx11[c] * x22_2 + sx21[c] * x12_2;
        w3 += sx11[c] * x22_3 + sx21[c] * x12_3;
    }
    float s0 = 1.f / (1.f + __expf(-w0));
    float s1 = 1.f / (1.f + __expf(-w1));
    float s2 = 1.f / (1.f + __expf(-w2));
    float s3 = 1.f / (1.f + __expf(-w3));
    #pragma unroll
    for (int c = 0; c < 8; c++) {
        float4 o;
        o.x = xr[c].x * s0; o.y = xr[c].y * s1; o.z = xr[c].z * s2; o.w = xr[c].w * s3;
        *(float4*)(out + base + ((size_t)c << 18)) = o;
    }
}

extern "C" void kernel_launch(void* const* d_in, const int* in_sizes, int n_in,
                              void* d_out, int out_size, void* d_ws, size_t ws_size,
                              hipStream_t stream) {
    const float* x   = (const float*)d_in[0];
    const float* w1  = (const float*)d_in[1];
    const float* b1  = (const float*)d_in[2];
    const float* g1  = (const float*)d_in[3];
    const float* be1 = (const float*)d_in[4];
    const float* w3  = (const float*)d_in[5];
    const float* b3  = (const float*)d_in[6];
    const float* g3  = (const float*)d_in[7];
    const float* be3 = (const float*)d_in[8];
    const float* gng = (const float*)d_in[9];
    const float* gnb = (const float*)d_in[10];
    float* out = (float*)d_out;

    float* ws     = (float*)d_ws;
    float* x2raw  = ws;                       // 33554432 floats
    // zeroed region (contiguous): catS, stats, gs, mrelu
    float* catS   = ws + 33554432;            // 24576
    float* stats  = catS + 24576;             // 16
    float* gs     = stats + 16;               // 256
    float* mrelu  = gs + 256;                 // 128
    // non-zeroed small buffers
    float* a      = mrelu + 128;              // 24576
    float* bnp    = a + 24576;                // 16
    float* x11    = bnp + 16;                 // 8
    float* x21    = x11 + 8;                  // 128
    float* attnp  = x21 + 128;                // 16

    hipMemsetAsync(catS, 0, (24576 + 16 + 256 + 128) * sizeof(float), stream);

    k_pools     <<<1024, 256, 0, stream>>>(x, catS);
    k_attn_stats<<<1, 256, 0, stream>>>(catS, w1, b1, g1, be1, attnp);
    k_attn_apply<<<96, 256, 0, stream>>>(catS, w1, b1, attnp, a);
    k_gnstats   <<<1024, 256, 0, stream>>>(x, a, gs);
    k_conv      <<<1024, 256, 0, stream>>>(x, w3, b3, x2raw, stats);
    k_finalize  <<<1, 64, 0, stream>>>(stats, g3, be3, gnb, bnp, x11);
    k_relumean  <<<1024, 256, 0, stream>>>(x2raw, bnp, mrelu);
    k_soft21    <<<1, 64, 0, stream>>>(mrelu, x21);
    k_final     <<<4096, 256, 0, stream>>>(x, x2raw, a, bnp, x11, x21, gs, gng, gnb, out);
}

// Round 3
// 598.767 us; speedup vs baseline: 1.9994x; 1.2117x over previous
//
#include <hip/hip_runtime.h>
#include <math.h>

#define VOL 262144        // 64^3
#define EPSF 1e-5f

typedef _Float16 half4_t __attribute__((ext_vector_type(4)));

__device__ __forceinline__ float waveReduceSum(float v) {
    #pragma unroll
    for (int off = 32; off > 0; off >>= 1) v += __shfl_down(v, off);
    return v;
}

// ---------------------------------------------------------------------------
// K0: weight transpose -> wT[(ic*8+oc)*27 + t] = w3[(oc*8+ic)*27 + t]
// (ic-major 216-float contiguous blocks -> bulk s_load in k_conv)
// ---------------------------------------------------------------------------
__global__ void k_wprep(const float* __restrict__ w3, float* __restrict__ wT) {
    int i = blockIdx.x * 256 + threadIdx.x;
    if (i < 1728) {
        int t = i % 27; int p = i / 27;
        int ic = p >> 3; int oc = p & 7;
        wT[i] = w3[(oc * 8 + ic) * 27 + t];
    }
}

// ---------------------------------------------------------------------------
// K1: directional pool SUMS. 1024 blocks: r = blk>>3, part = blk&7.
// ---------------------------------------------------------------------------
__global__ void k_pools(const float* __restrict__ x, float* __restrict__ catS) {
    int r = blockIdx.x >> 3, part = blockIdx.x & 7;
    const float* base = x + (size_t)r * VOL + ((size_t)(part * 8) << 12);
    __shared__ float sd[8], sh[64], sw[64];
    int tid = threadIdx.x;
    if (tid < 8) sd[tid] = 0.f;
    if (tid < 64) { sh[tid] = 0.f; sw[tid] = 0.f; }
    __syncthreads();
    int w4 = (tid & 15) * 4;
    int hr = tid >> 4;
    float wacc[4] = {0.f, 0.f, 0.f, 0.f};
    float hacc[4] = {0.f, 0.f, 0.f, 0.f};
    for (int p = 0; p < 8; p++) {
        const float* pd = base + (p << 12);
        float psum = 0.f;
        #pragma unroll
        for (int j = 0; j < 4; j++) {
            int hh = hr + j * 16;
            float4 v = *(const float4*)(pd + (hh << 6) + w4);
            float s = v.x + v.y + v.z + v.w;
            hacc[j] += s; psum += s;
            wacc[0] += v.x; wacc[1] += v.y; wacc[2] += v.z; wacc[3] += v.w;
        }
        psum = waveReduceSum(psum);
        if ((tid & 63) == 0) atomicAdd(&sd[p], psum);
    }
    #pragma unroll
    for (int j = 0; j < 4; j++) atomicAdd(&sh[hr + j * 16], hacc[j]);
    #pragma unroll
    for (int k = 0; k < 4; k++) atomicAdd(&sw[w4 + k], wacc[k]);
    __syncthreads();
    float* o = catS + (size_t)r * 192;
    if (tid < 8)                       atomicAdd(&o[part * 8 + tid], sd[tid]);
    else if (tid >= 64 && tid < 128)   atomicAdd(&o[64 + tid - 64], sh[tid - 64]);
    else if (tid >= 128 && tid < 192)  atomicAdd(&o[128 + tid - 128], sw[tid - 128]);
}

// ---------------------------------------------------------------------------
// K2a: BN stats of hwd. Single block. attnp[0..7]=scale, [8..15]=shift.
// ---------------------------------------------------------------------------
__global__ void k_attn_stats(const float* __restrict__ catS, const float* __restrict__ w1,
                             const float* __restrict__ b1, const float* __restrict__ g1,
                             const float* __restrict__ be1, float* __restrict__ attnp) {
    __shared__ float r1[256], r2[256];
    __shared__ float wsm[64];
    int tid = threadIdx.x;
    if (tid < 64) wsm[tid] = w1[tid] * (1.f / 4096.f);
    __syncthreads();
    int o = tid >> 5, j = tid & 31;
    float s1 = 0.f, s2 = 0.f;
    for (int idx = j; idx < 3072; idx += 32) {
        int bgI = idx / 192, s = idx - bgI * 192;
        const float* cp = catS + (size_t)bgI * 1536 + s;
        float h = b1[o];
        #pragma unroll
        for (int i = 0; i < 8; i++) h += wsm[o * 8 + i] * cp[i * 192];
        s1 += h; s2 += h * h;
    }
    r1[tid] = s1; r2[tid] = s2;
    __syncthreads();
    for (int st = 16; st > 0; st >>= 1) {
        if (j < st) { r1[tid] += r1[tid + st]; r2[tid] += r2[tid + st]; }
        __syncthreads();
    }
    if (j == 0) {
        float mean = r1[tid] / 3072.f;
        float var  = r2[tid] / 3072.f - mean * mean;
        float sc = g1[o] * rsqrtf(var + EPSF);
        attnp[o] = sc; attnp[8 + o] = be1[o] - mean * sc;
    }
}

// K2b: apply BN+relu+sigmoid -> a.
__global__ void k_attn_apply(const float* __restrict__ catS, const float* __restrict__ w1,
                             const float* __restrict__ b1, const float* __restrict__ attnp,
                             float* __restrict__ aout) {
    __shared__ float wsm[64];
    int tid = threadIdx.x;
    if (tid < 64) wsm[tid] = w1[tid] * (1.f / 4096.f);
    __syncthreads();
    int e = blockIdx.x * 256 + tid;
    int bgI = e / 1536;
    int rem = e - bgI * 1536;
    int oo = rem / 192;
    int s = rem - oo * 192;
    const float* cp = catS + (size_t)bgI * 1536 + s;
    float h = b1[oo];
    #pragma unroll
    for (int i = 0; i < 8; i++) h += wsm[oo * 8 + i] * cp[i * 192];
    float v = attnp[oo] * h + attnp[8 + oo];
    v = fmaxf(v, 0.f);
    aout[e] = 1.f / (1.f + __expf(-v));
}

// ---------------------------------------------------------------------------
// K3: GroupNorm raw sums of y = x * a_d*a_h*a_w. 1024 blocks.
// ---------------------------------------------------------------------------
__global__ void k_gnstats(const float* __restrict__ x, const float* __restrict__ a,
                          float* __restrict__ gs) {
    int r = blockIdx.x >> 3, part = blockIdx.x & 7;
    const float* xp = x + (size_t)r * VOL + ((size_t)part << 15);
    __shared__ float A[192];
    __shared__ float wred[8];
    int tid = threadIdx.x;
    if (tid < 192) A[tid] = a[(size_t)r * 192 + tid];
    __syncthreads();
    float s1 = 0.f, s2 = 0.f;
    for (int it = 0; it < 32; it++) {
        int e4 = it * 256 + tid;
        int n = e4 * 4;
        int dl = n >> 12;
        int h = (n >> 6) & 63, w = n & 63;
        float4 v = *(const float4*)(xp + n);
        float adh = A[part * 8 + dl] * A[64 + h];
        float y0 = v.x * adh * A[128 + w];
        float y1 = v.y * adh * A[128 + w + 1];
        float y2 = v.z * adh * A[128 + w + 2];
        float y3 = v.w * adh * A[128 + w + 3];
        s1 += y0 + y1 + y2 + y3;
        s2 += y0 * y0 + y1 * y1 + y2 * y2 + y3 * y3;
    }
    s1 = waveReduceSum(s1); s2 = waveReduceSum(s2);
    int lane = tid & 63, wid = tid >> 6;
    if (lane == 0) { wred[wid] = s1; wred[4 + wid] = s2; }
    __syncthreads();
    if (tid == 0) {
        atomicAdd(&gs[r],       wred[0] + wred[1] + wred[2] + wred[3]);
        atomicAdd(&gs[128 + r], wred[4] + wred[5] + wred[6] + wred[7]);
    }
}

// ---------------------------------------------------------------------------
// K4: 3x3x3 SAME conv, rolling-d, 4-wide w per thread (float4 loads).
// 512 blocks: bg(16) x hc(4) x dc(8). Thread: wq = tid&15 (w-quad), hr = tid>>4.
// Weights from ic-major wT -> bulk scalar loads; each weight amortized x4.
// Output fp16; BN sums accumulated in fp32 pre-rounding.
// ---------------------------------------------------------------------------
__global__ __launch_bounds__(256) void k_conv(const float* __restrict__ x,
                                              const float* __restrict__ wT,
                                              const float* __restrict__ b3,
                                              _Float16* __restrict__ x2h,
                                              float* __restrict__ stats) {
    __shared__ float wred[64];
    int blk = blockIdx.x;
    int bg = blk >> 5;
    int rem = blk & 31;
    int hc = rem >> 3;
    int dc = rem & 7;
    int d0 = dc * 8;
    int tid = threadIdx.x;
    int wq = tid & 15;
    int hr = tid >> 4;
    int h = hc * 16 + hr;
    int w0 = wq * 4;
    const float* xb = x + ((size_t)bg << 21);
    float acc[3][8][4];
    float ps[8], pq[8];
    #pragma unroll
    for (int c = 0; c < 8; c++) { ps[c] = 0.f; pq[c] = 0.f; }

#define STEP(I, ZI, YI, XI)                                                        \
    {                                                                              \
        int dd = d0 - 1 + (I);                                                     \
        bool dvalid = (dd >= 0) && (dd < 64);                                      \
        _Pragma("unroll")                                                          \
        for (int c = 0; c < 8; c++) {                                              \
            float bv = b3[c];                                                      \
            acc[ZI][c][0] = bv; acc[ZI][c][1] = bv;                                \
            acc[ZI][c][2] = bv; acc[ZI][c][3] = bv;                                \
        }                                                                          \
        _Pragma("unroll 1")                                                        \
        for (int ic = 0; ic < 8; ic++) {                                           \
            const float* pl = xb + ((size_t)ic << 18) + ((size_t)(dd & 63) << 12) + w0; \
            float v6[3][6];                                                        \
            _Pragma("unroll")                                                      \
            for (int kh = 0; kh < 3; kh++) {                                       \
                int hh = h + kh - 1;                                               \
                float4 vx = {0.f, 0.f, 0.f, 0.f};                                  \
                if (dvalid && hh >= 0 && hh < 64)                                  \
                    vx = *(const float4*)(pl + (hh << 6));                         \
                float vm = __shfl_up(vx.w, 1);                                     \
                float vp = __shfl_down(vx.x, 1);                                   \
                if (wq == 0)  vm = 0.f;                                            \
                if (wq == 15) vp = 0.f;                                            \
                v6[kh][0] = vm; v6[kh][1] = vx.x; v6[kh][2] = vx.y;                \
                v6[kh][3] = vx.z; v6[kh][4] = vx.w; v6[kh][5] = vp;                \
            }                                                                      \
            const float* wb = wT + ic * 216;                                       \
            _Pragma("unroll")                                                      \
            for (int oc = 0; oc < 8; oc++) {                                       \
                const float* wo = wb + oc * 27;                                    \
                _Pragma("unroll")                                                  \
                for (int kh = 0; kh < 3; kh++) {                                   \
                    _Pragma("unroll")                                              \
                    for (int kw = 0; kw < 3; kw++) {                               \
                        float wz = wo[kh * 3 + kw];                                \
                        float wy = wo[9 + kh * 3 + kw];                            \
                        float wx = wo[18 + kh * 3 + kw];                           \
                        _Pragma("unroll")                                          \
                        for (int j = 0; j < 4; j++) {                              \
                            float vv = v6[kh][kw + j];                             \
                            acc[ZI][oc][j] += vv * wz;                             \
                            acc[YI][oc][j] += vv * wy;                             \
                            acc[XI][oc][j] += vv * wx;                             \
                        }                                                          \
                    }                                                              \
                }                                                                  \
            }                                                                      \
        }                                                                          \
        if ((I) >= 2) {                                                            \
            int dO = d0 - 2 + (I);                                                 \
            size_t base = (((size_t)bg * 8) << 18) + ((size_t)dO << 12)            \
                        + (h << 6) + w0;                                           \
            _Pragma("unroll")                                                      \
            for (int oc = 0; oc < 8; oc++) {                                       \
                float a0 = acc[XI][oc][0], a1 = acc[XI][oc][1];                    \
                float a2 = acc[XI][oc][2], a3 = acc[XI][oc][3];                    \
                half4_t hv;                                                        \
                hv.x = (_Float16)a0; hv.y = (_Float16)a1;                          \
                hv.z = (_Float16)a2; hv.w = (_Float16)a3;                          \
                *(half4_t*)(x2h + base + ((size_t)oc << 18)) = hv;                 \
                ps[oc] += a0 + a1 + a2 + a3;                                       \
                pq[oc] += a0 * a0 + a1 * a1 + a2 * a2 + a3 * a3;                   \
            }                                                                      \
        }                                                                          \
    }

    for (int i3 = 0; i3 < 9; i3 += 3) {
        STEP(i3 + 0, 0, 2, 1)
        STEP(i3 + 1, 1, 0, 2)
        STEP(i3 + 2, 2, 1, 0)
    }
    STEP(9, 0, 2, 1)
#undef STEP

    int lane = tid & 63, wid = tid >> 6;
    #pragma unroll
    for (int q = 0; q < 8; q++) {
        float v1 = waveReduceSum(ps[q]);
        float v2 = waveReduceSum(pq[q]);
        if (lane == 0) { wred[wid * 16 + q] = v1; wred[wid * 16 + 8 + q] = v2; }
    }
    __syncthreads();
    if (tid < 16) {
        float t = wred[tid] + wred[16 + tid] + wred[32 + tid] + wred[48 + tid];
        atomicAdd(&stats[tid], t);
    }
}

// K5: finalize BN3 scale/shift; x11 = softmax(gn_b).
__global__ void k_finalize(const float* __restrict__ stats, const float* __restrict__ g3,
                           const float* __restrict__ be3, const float* __restrict__ gnb,
                           float* __restrict__ bnp, float* __restrict__ x11) {
    int tid = threadIdx.x;
    if (tid < 8) {
        float N = 16.f * (float)VOL;
        float mean = stats[tid] / N;
        float var  = stats[8 + tid] / N - mean * mean;
        float sc = g3[tid] * rsqrtf(var + EPSF);
        bnp[tid] = sc; bnp[8 + tid] = be3[tid] - mean * sc;
    }
    if (tid == 0) {
        float m = -1e30f;
        for (int c = 0; c < 8; c++) m = fmaxf(m, gnb[c]);
        float e[8], sum = 0.f;
        for (int c = 0; c < 8; c++) { e[c] = __expf(gnb[c] - m); sum += e[c]; }
        for (int c = 0; c < 8; c++) x11[c] = e[c] / sum;
    }
}

// K6: per-row sum of relu(bn(x2h)) -> mrelu. 1024 blocks, half4 reads.
__global__ void k_relumean(const _Float16* __restrict__ x2h, const float* __restrict__ bnp,
                           float* __restrict__ mrelu) {
    int blk = blockIdx.x;
    int r = blk >> 3, part = blk & 7;
    int cc = r & 7;
    float sc = bnp[cc], sh = bnp[8 + cc];
    const half4_t* p = (const half4_t*)(x2h + (size_t)r * VOL + (size_t)part * 32768);
    int tid = threadIdx.x;
    float s = 0.f;
    for (int it = 0; it < 32; it++) {
        half4_t v = p[it * 256 + tid];
        s += fmaxf(sc * (float)v.x + sh, 0.f) + fmaxf(sc * (float)v.y + sh, 0.f)
           + fmaxf(sc * (float)v.z + sh, 0.f) + fmaxf(sc * (float)v.w + sh, 0.f);
    }
    s = waveReduceSum(s);
    __shared__ float wred[4];
    int lane = tid & 63, wid = tid >> 6;
    if (lane == 0) wred[wid] = s;
    __syncthreads();
    if (tid == 0) atomicAdd(&mrelu[r], wred[0] + wred[1] + wred[2] + wred[3]);
}

// K6b: x21[bg][c] = softmax_c(mrelu[bg*8+c]/VOL)
__global__ void k_soft21(const float* __restrict__ mrelu, float* __restrict__ x21) {
    int bg = threadIdx.x;
    if (bg < 16) {
        float v[8], m = -1e30f;
        for (int c = 0; c < 8; c++) { v[c] = mrelu[bg * 8 + c] / (float)VOL; m = fmaxf(m, v[c]); }
        float sum = 0.f;
        for (int c = 0; c < 8; c++) { v[c] = __expf(v[c] - m); sum += v[c]; }
        for (int c = 0; c < 8; c++) x21[bg * 8 + c] = v[c] / sum;
    }
}

// ---------------------------------------------------------------------------
// K7: final fused: weights = x11·x22 + x21·x12; out = x * sigmoid(weights).
// ---------------------------------------------------------------------------
__global__ void k_final(const float* __restrict__ x, const _Float16* __restrict__ x2h,
                        const float* __restrict__ a, const float* __restrict__ bnp,
                        const float* __restrict__ x11g, const float* __restrict__ x21g,
                        const float* __restrict__ gs, const float* __restrict__ gng,
                        const float* __restrict__ gnb, float* __restrict__ out) {
    int bg = blockIdx.x >> 8;
    int seg = blockIdx.x & 255;
    int tid = threadIdx.x;
    __shared__ float sa[1536];
    __shared__ float sc_[8], sh_[8], sx11[8], sx21[8], sgsc[8], sgsh[8];
    const float* ap = a + (size_t)bg * 1536;
    for (int i = tid; i < 1536; i += 256) sa[i] = ap[i];
    if (tid < 8) {
        int r = bg * 8 + tid;
        sc_[tid] = bnp[tid]; sh_[tid] = bnp[8 + tid];
        sx11[tid] = x11g[tid]; sx21[tid] = x21g[r];
        float mean = gs[r] / (float)VOL;
        float var  = gs[128 + r] / (float)VOL - mean * mean;
        float gr = rsqrtf(var + EPSF) * gng[tid];
        sgsc[tid] = gr; sgsh[tid] = gnb[tid] - mean * gr;
    }
    __syncthreads();
    int n = (seg * 256 + tid) * 4;
    int d = n >> 12, h = (n >> 6) & 63, w = n & 63;
    size_t base = ((size_t)bg << 21) + n;
    float4 xr[8];
    float w0 = 0.f, w1 = 0.f, w2 = 0.f, w3 = 0.f;
    #pragma unroll
    for (int c = 0; c < 8; c++) {
        size_t idx = base + ((size_t)c << 18);
        float4 xv = *(const float4*)(x + idx);
        half4_t v2 = *(const half4_t*)(x2h + idx);
        xr[c] = xv;
        float adh = sa[c * 192 + d] * sa[c * 192 + 64 + h] * sgsc[c];
        float x22_0 = fmaxf(sc_[c] * (float)v2.x + sh_[c], 0.f);
        float x22_1 = fmaxf(sc_[c] * (float)v2.y + sh_[c], 0.f);
        float x22_2 = fmaxf(sc_[c] * (float)v2.z + sh_[c], 0.f);
        float x22_3 = fmaxf(sc_[c] * (float)v2.w + sh_[c], 0.f);
        float x12_0 = xv.x * (adh * sa[c * 192 + 128 + w])     + sgsh[c];
        float x12_1 = xv.y * (adh * sa[c * 192 + 128 + w + 1]) + sgsh[c];
        float x12_2 = xv.z * (adh * sa[c * 192 + 128 + w + 2]) + sgsh[c];
        float x12_3 = xv.w * (adh * sa[c * 192 + 128 + w + 3]) + sgsh[c];
        w0 += sx11[c] * x22_0 + sx21[c] * x12_0;
        w1 += sx11[c] * x22_1 + sx21[c] * x12_1;
        w2 += sx11[c] * x22_2 + sx21[c] * x12_2;
        w3 += sx11[c] * x22_3 + sx21[c] * x12_3;
    }
    float s0 = 1.f / (1.f + __expf(-w0));
    float s1 = 1.f / (1.f + __expf(-w1));
    float s2 = 1.f / (1.f + __expf(-w2));
    float s3 = 1.f / (1.f + __expf(-w3));
    #pragma unroll
    for (int c = 0; c < 8; c++) {
        float4 o;
        o.x = xr[c].x * s0; o.y = xr[c].y * s1; o.z = xr[c].z * s2; o.w = xr[c].w * s3;
        *(float4*)(out + base + ((size_t)c << 18)) = o;
    }
}

extern "C" void kernel_launch(void* const* d_in, const int* in_sizes, int n_in,
                              void* d_out, int out_size, void* d_ws, size_t ws_size,
                              hipStream_t stream) {
    const float* x   = (const float*)d_in[0];
    const float* w1  = (const float*)d_in[1];
    const float* b1  = (const float*)d_in[2];
    const float* g1  = (const float*)d_in[3];
    const float* be1 = (const float*)d_in[4];
    const float* w3  = (const float*)d_in[5];
    const float* b3  = (const float*)d_in[6];
    const float* g3  = (const float*)d_in[7];
    const float* be3 = (const float*)d_in[8];
    const float* gng = (const float*)d_in[9];
    const float* gnb = (const float*)d_in[10];
    float* out = (float*)d_out;

    float* wsf       = (float*)d_ws;
    _Float16* x2h    = (_Float16*)d_ws;       // 33554432 halfs = 16777216 float-slots
    // zeroed region (contiguous): catS, stats, gs, mrelu
    float* catS   = wsf + 16777216;           // 24576
    float* stats  = catS + 24576;             // 16
    float* gs     = stats + 16;               // 256
    float* mrelu  = gs + 256;                 // 128
    // non-zeroed small buffers
    float* a      = mrelu + 128;              // 24576
    float* bnp    = a + 24576;                // 16
    float* x11    = bnp + 16;                 // 8
    float* x21    = x11 + 8;                  // 128
    float* attnp  = x21 + 128;                // 16
    float* wT     = attnp + 16;               // 1728

    hipMemsetAsync(catS, 0, (24576 + 16 + 256 + 128) * sizeof(float), stream);

    k_wprep     <<<7, 256, 0, stream>>>(w3, wT);
    k_pools     <<<1024, 256, 0, stream>>>(x, catS);
    k_attn_stats<<<1, 256, 0, stream>>>(catS, w1, b1, g1, be1, attnp);
    k_attn_apply<<<96, 256, 0, stream>>>(catS, w1, b1, attnp, a);
    k_gnstats   <<<1024, 256, 0, stream>>>(x, a, gs);
    k_conv      <<<512, 256, 0, stream>>>(x, wT, b3, x2h, stats);
    k_finalize  <<<1, 64, 0, stream>>>(stats, g3, be3, gnb, bnp, x11);
    k_relumean  <<<1024, 256, 0, stream>>>(x2h, bnp, mrelu);
    k_soft21    <<<1, 64, 0, stream>>>(mrelu, x21);
    k_final     <<<4096, 256, 0, stream>>>(x, x2h, a, bnp, x11, x21, gs, gng, gnb, out);
}